// Round 14
// baseline (56.849 us; speedup 1.0000x reference)
//
#include <hip/hip_runtime.h>

namespace {

constexpr int B = 8, C = 4, K = 5;
constexpr int HW = 512 * 1024;     // pixels per (b,c) plane
constexpr int NG = HW / 4;         // float4 groups per plane (131072)
constexpr int NT = 256;            // threads per block
constexpr int GPB = 256;           // blocks per batch
constexpr int NBLK = GPB * B;      // 2048 blocks = 8/CU -> co-resident
constexpr int GRP_BLK = NG / GPB;  // 512 groups (2048 pixels) per block
constexpr int IT = GRP_BLK / NT;   // 2 iterations of 1 group/thread
constexpr int SS = 4;              // atomic sub-slots (64-long RMW chains)
constexpr int LINE = 32;           // floats per 128B line
constexpr float DV = 0.5f;         // DELTA_V
constexpr float DD = 3.0f;         // DELTA_D
constexpr double FXST = 16777216.0;       // 2^24 stats fixed-point scale
constexpr double FXSV = 1099511627776.0;  // 2^40 var fixed-point scale

using u64 = unsigned long long;

// ws layout; every RMW slot owns a 128B line; all zeroed by zero_kernel
// (node 0). All cross-block sums are INTEGER fixed-point (associative ->
// deterministic). Proven R10-R13 machinery.
constexpr int ST_OFF = 0;                              // [B*25*SS] u64
constexpr int IACC_OFF = ST_OFF + B * 25 * SS * LINE;  // [B*SS] u64
constexpr int C1S_OFF = IACC_OFF + B * SS * LINE;      // [B*SS] u32
constexpr int C1M_OFF = C1S_OFF + B * SS * LINE;       // [B] u32
constexpr int C2S_OFF = C1M_OFF + B * LINE;            // [B*SS] u32
constexpr int GC_OFF = C2S_OFF + B * SS * LINE;        // 1 u32
constexpr int WS_FLOATS = GC_OFF + LINE;               // ~28.9K floats

__device__ __forceinline__ float wave_reduce(float v) {
#pragma unroll
  for (int m = 32; m; m >>= 1) v += __shfl_xor(v, m, 64);
  return v;
}

__device__ __forceinline__ u64 aload64(const float* p) {
  return __hip_atomic_load(reinterpret_cast<const u64*>(p), __ATOMIC_RELAXED,
                           __HIP_MEMORY_SCOPE_AGENT);
}

// bf16 pack (round-to-nearest-even) / unpack
__device__ __forceinline__ unsigned rtne16(float x) {
  const unsigned u = __float_as_uint(x);
  return u + 0x7fffu + ((u >> 16) & 1u);
}
__device__ __forceinline__ unsigned pk(float lo, float hi) {
  return (rtne16(lo) >> 16) | (rtne16(hi) & 0xffff0000u);
}
__device__ __forceinline__ float bflo(unsigned p) {
  return __uint_as_float(p << 16);
}
__device__ __forceinline__ float bfhi(unsigned p) {
  return __uint_as_float(p & 0xffff0000u);
}

__global__ void zero_kernel(float* __restrict__ ws) {
  const int i = blockIdx.x * blockDim.x + threadIdx.x;
  if (i < WS_FLOATS) ws[i] = 0.f;
}

// Fused: phase1 streams HBM once (fp32 stats + bf16 LDS cache) ->
// per-batch spin barrier -> phase3 re-reads pixels from LDS only.
__global__ __launch_bounds__(NT, 8) void fused_kernel(
    const float* __restrict__ emb, const int* __restrict__ lab,
    float* __restrict__ ws, float* __restrict__ out) {
  const int b = blockIdx.x >> 8, bxl = blockIdx.x & (GPB - 1);
  const int tid = threadIdx.x, wv = tid >> 6, ln = tid & 63;

  __shared__ unsigned e01[GRP_BLK * 4];  // 8 KB: pixel -> bf16(c0,c1)
  __shared__ unsigned e23[GRP_BLK * 4];  // 8 KB: pixel -> bf16(c2,c3)
  __shared__ unsigned labp[GRP_BLK];     // 2 KB: 4 labels/u32
  __shared__ float red[4][25];
  __shared__ float stot[25];
  __shared__ float sm[K][C];
  __shared__ float scnt[K];
  __shared__ float rcnt[8];  // rcnt[l] = (l==0) ? 0 : 1/cnt[l-1]
  __shared__ float red2[4];
  __shared__ unsigned lastFlag;

  const float4* __restrict__ ep =
      reinterpret_cast<const float4*>(emb + (size_t)b * C * HW);
  const int4* __restrict__ lp =
      reinterpret_cast<const int4*>(lab + (size_t)b * HW);

  // ---------------- Phase 1: single HBM sweep ----------------
  float acc[25];  // [k][{c0..c3,cnt}] flat, compile-time indexed only
#pragma unroll
  for (int i = 0; i < 25; i++) acc[i] = 0.f;
  auto accum1 = [&](int l, float v0, float v1, float v2, float v3) {
#pragma unroll
    for (int k = 0; k < K; k++) {  // branchless predicated accumulate
      const float m = (l == k + 1) ? 1.f : 0.f;
      acc[k * 5 + 0] = fmaf(m, v0, acc[k * 5 + 0]);
      acc[k * 5 + 1] = fmaf(m, v1, acc[k * 5 + 1]);
      acc[k * 5 + 2] = fmaf(m, v2, acc[k * 5 + 2]);
      acc[k * 5 + 3] = fmaf(m, v3, acc[k * 5 + 3]);
      acc[k * 5 + 4] += m;
    }
  };

#pragma unroll 1
  for (int it = 0; it < IT; it++) {
    const int lg = it * NT + tid;      // local group (coalesced per iter)
    const int g = bxl * GRP_BLK + lg;  // group within batch
    const int4 la = lp[g];
    const float4 e0 = ep[g], e1 = ep[NG + g], e2 = ep[2 * NG + g],
                 e3 = ep[3 * NG + g];
    accum1(la.x, e0.x, e1.x, e2.x, e3.x);
    accum1(la.y, e0.y, e1.y, e2.y, e3.y);
    accum1(la.z, e0.z, e1.z, e2.z, e3.z);
    accum1(la.w, e0.w, e1.w, e2.w, e3.w);
    uint4 w01, w23;
    w01.x = pk(e0.x, e1.x); w23.x = pk(e2.x, e3.x);
    w01.y = pk(e0.y, e1.y); w23.y = pk(e2.y, e3.y);
    w01.z = pk(e0.z, e1.z); w23.z = pk(e2.z, e3.z);
    w01.w = pk(e0.w, e1.w); w23.w = pk(e2.w, e3.w);
    *reinterpret_cast<uint4*>(&e01[lg * 4]) = w01;
    *reinterpret_cast<uint4*>(&e23[lg * 4]) = w23;
    labp[lg] = (unsigned)(la.x & 0xff) | ((unsigned)(la.y & 0xff) << 8) |
               ((unsigned)(la.z & 0xff) << 16) |
               ((unsigned)(la.w & 0xff) << 24);
  }

#pragma unroll
  for (int i = 0; i < 25; i++) {
    const float v = wave_reduce(acc[i]);
    if (ln == 0) red[wv][i] = v;
  }
  __syncthreads();
  if (tid < 25) {  // publish stats: integer atomicAdd, 64-long chains
    const float t =
        (red[0][tid] + red[1][tid]) + (red[2][tid] + red[3][tid]);
    const long long q = (long long)((double)t * FXST);
    atomicAdd(reinterpret_cast<u64*>(
                  ws + ST_OFF +
                  ((size_t)(b * 25 + tid) * SS + (bxl & (SS - 1))) * LINE),
              (u64)q);
  }

  // per-batch barrier: two-level arrival + relaxed spin (proven machinery)
  if (tid == 0) {
    asm volatile("s_waitcnt vmcnt(0)" ::: "memory");  // drain publishes
    unsigned* c1s = reinterpret_cast<unsigned*>(
        ws + C1S_OFF + ((size_t)b * SS + (bxl & (SS - 1))) * LINE);
    const unsigned olds = atomicAdd(c1s, 1u);
    if (olds == (unsigned)(GPB / SS - 1)) {  // sub-group finisher
      asm volatile("s_waitcnt vmcnt(0)" ::: "memory");
      atomicAdd(reinterpret_cast<unsigned*>(ws + C1M_OFF + (size_t)b * LINE),
                1u);
    }
    const unsigned* c1m =
        reinterpret_cast<const unsigned*>(ws + C1M_OFF + (size_t)b * LINE);
    while (__hip_atomic_load(c1m, __ATOMIC_RELAXED,
                             __HIP_MEMORY_SCOPE_AGENT) < (unsigned)SS) {
      __builtin_amdgcn_s_sleep(2);
    }
  }
  __syncthreads();
  asm volatile("" ::: "memory");

  // ---------------- Phase 2: read batch stats -> means ----------------
  if (tid < 25) {
    long long s = 0;
#pragma unroll
    for (int j = 0; j < SS; j++)
      s += (long long)aload64(ws + ST_OFF +
                              ((size_t)(b * 25 + tid) * SS + j) * LINE);
    stot[tid] = (float)((double)s / FXST);
  }
  __syncthreads();
  if (tid < K * C) {
    const int k = tid / C, c = tid % C;
    sm[k][c] = stot[k * 5 + c] / stot[k * 5 + 4];
  }
  if (tid < K) scnt[tid] = stot[tid * 5 + 4];
  if (tid < 8) rcnt[tid] = 0.f;
  __syncthreads();
  if (tid < K) rcnt[tid + 1] = 1.f / scnt[tid];
  __syncthreads();

  // ------- Phase 3: LDS-only sweep, single accumulator per thread -------
  float vacc = 0.f;  // sum of t^2/cnt[lane] (exactly one lane per pixel)
  auto accum2 = [&](int l, float v0, float v1, float v2, float v3) {
    const int kk = (l > 0) ? (l - 1) : 0;  // safe index; l==0 -> rcnt[0]==0
    const float d0 = v0 - sm[kk][0];
    const float d1 = v1 - sm[kk][1];
    const float d2 = v2 - sm[kk][2];
    const float d3 = v3 - sm[kk][3];
    const float t =
        fmaxf(sqrtf(d0 * d0 + d1 * d1 + d2 * d2 + d3 * d3) - DV, 0.f);
    vacc = fmaf(t * t, rcnt[l], vacc);
  };
#pragma unroll 1
  for (int it = 0; it < IT; it++) {
    const int lg = it * NT + tid;
    const uint4 r01 = *reinterpret_cast<const uint4*>(&e01[lg * 4]);
    const uint4 r23 = *reinterpret_cast<const uint4*>(&e23[lg * 4]);
    const unsigned lw = labp[lg];
    accum2((int)(lw & 0xffu), bflo(r01.x), bfhi(r01.x), bflo(r23.x),
           bfhi(r23.x));
    accum2((int)((lw >> 8) & 0xffu), bflo(r01.y), bfhi(r01.y), bflo(r23.y),
           bfhi(r23.y));
    accum2((int)((lw >> 16) & 0xffu), bflo(r01.z), bfhi(r01.z), bflo(r23.z),
           bfhi(r23.z));
    accum2((int)((lw >> 24) & 0xffu), bflo(r01.w), bfhi(r01.w), bflo(r23.w),
           bfhi(r23.w));
  }
  {
    const float v = wave_reduce(vacc);
    if (ln == 0) red2[wv] = v;
  }
  __syncthreads();

  if (tid == 0) {
    const float sblk = (red2[0] + red2[1]) + (red2[2] + red2[3]);
    const u64 fx = (u64)(long long)((double)sblk * FXSV);
    atomicAdd(reinterpret_cast<u64*>(
                  ws + IACC_OFF + ((size_t)b * SS + (bxl & (SS - 1))) * LINE),
              fx);
    asm volatile("s_waitcnt vmcnt(0)" ::: "memory");
    unsigned* c2s = reinterpret_cast<unsigned*>(
        ws + C2S_OFF + ((size_t)b * SS + (bxl & (SS - 1))) * LINE);
    const unsigned olds = atomicAdd(c2s, 1u);
    unsigned lf = 0u;
    if (olds == (unsigned)(GPB / SS - 1)) {
      asm volatile("s_waitcnt vmcnt(0)" ::: "memory");
      unsigned* gc = reinterpret_cast<unsigned*>(ws + GC_OFF);
      const unsigned oldg = atomicAdd(gc, 1u);
      lf = (oldg == (unsigned)(B * SS - 1)) ? 1u : 0u;
    }
    lastFlag = lf;
  }
  __syncthreads();
  if (!lastFlag) return;

  // ---------------- Finalize (unique global-last block) ----------------
  __shared__ float stF[B * 25];
  __shared__ float sb[B];
  if (tid < B * 25) {
    long long s = 0;
#pragma unroll
    for (int j = 0; j < SS; j++)
      s += (long long)aload64(ws + ST_OFF + ((size_t)tid * SS + j) * LINE);
    stF[tid] = (float)((double)s / FXST);
  }
  if (tid < B) {
    long long s = 0;
#pragma unroll
    for (int j = 0; j < SS; j++)
      s += (long long)aload64(ws + IACC_OFF + ((size_t)tid * SS + j) * LINE);
    sb[tid] = (float)((double)s / FXSV);
  }
  __syncthreads();
  if (tid != 0) return;

  float v = 0.f, d = 0.f;
  for (int bb = 0; bb < B; bb++) {
    float m[K][C];
#pragma unroll
    for (int k = 0; k < K; k++) {
      const float cnt = stF[bb * 25 + k * 5 + 4];
#pragma unroll
      for (int c = 0; c < C; c++) m[k][c] = stF[bb * 25 + k * 5 + c] / cnt;
    }
    float p = 0.f;
#pragma unroll
    for (int i = 0; i < K; i++) {
#pragma unroll
      for (int j = 0; j < K; j++) {
        if (i == j) continue;  // diagonal term is exactly 0
        float dd = 0.f;
#pragma unroll
        for (int c = 0; c < C; c++) {
          const float t = m[i][c] - m[j][c];
          dd += t * t;
        }
        const float r = fmaxf(DD - sqrtf(dd), 0.f);
        p += r * r;
      }
    }
    v = (v + sb[bb]) / (float)K;
    d = (d + p) / (float)(2 * K * (K - 1));
  }
  out[0] = v / (float)B;
  out[1] = d / (float)B;
}

}  // namespace

extern "C" void kernel_launch(void* const* d_in, const int* in_sizes, int n_in,
                              void* d_out, int out_size, void* d_ws,
                              size_t ws_size, hipStream_t stream) {
  const float* emb = (const float*)d_in[0];
  const int* lab = (const int*)d_in[1];
  float* out = (float*)d_out;
  float* ws = (float*)d_ws;

  zero_kernel<<<(WS_FLOATS + NT - 1) / NT, NT, 0, stream>>>(ws);
  fused_kernel<<<NBLK, NT, 0, stream>>>(emb, lab, ws, out);
}

// Round 15
// 55.957 us; speedup vs baseline: 1.0159x; 1.0159x over previous
//
#include <hip/hip_runtime.h>

namespace {

constexpr int B = 8, C = 4, K = 5;
constexpr int HW = 512 * 1024;     // pixels per (b,c) plane
constexpr int NG = HW / 4;         // float4 groups per plane (131072)
constexpr int NT = 256;            // threads per block
constexpr int GPB = 256;           // blocks per batch
constexpr int NBLK = GPB * B;      // 2048 blocks = 8/CU -> co-resident
constexpr int GRP_BLK = NG / GPB;  // 512 groups (2048 pixels) per block
constexpr int SS = 4;              // atomic sub-slots (64-long RMW chains)
constexpr int LINE = 32;           // floats per 128B line
constexpr float DV = 0.5f;         // DELTA_V
constexpr float DD = 3.0f;         // DELTA_D
constexpr double FXST = 16777216.0;       // 2^24 stats fixed-point scale
constexpr double FXSV = 1099511627776.0;  // 2^40 var fixed-point scale

using u64 = unsigned long long;

// ws layout; every RMW slot owns a 128B line; all zeroed by zero_kernel
// (node 0). All cross-block sums are INTEGER fixed-point (associative ->
// deterministic). Proven R10-R14 machinery.
constexpr int ST_OFF = 0;                              // [B*25*SS] u64
constexpr int IACC_OFF = ST_OFF + B * 25 * SS * LINE;  // [B*SS] u64
constexpr int C1S_OFF = IACC_OFF + B * SS * LINE;      // [B*SS] u32
constexpr int C1M_OFF = C1S_OFF + B * SS * LINE;       // [B] u32
constexpr int C2S_OFF = C1M_OFF + B * LINE;            // [B*SS] u32
constexpr int GC_OFF = C2S_OFF + B * SS * LINE;        // 1 u32
constexpr int WS_FLOATS = GC_OFF + LINE;               // ~28.9K floats

__device__ __forceinline__ float wave_reduce(float v) {
#pragma unroll
  for (int m = 32; m; m >>= 1) v += __shfl_xor(v, m, 64);
  return v;
}

__device__ __forceinline__ u64 aload64(const float* p) {
  return __hip_atomic_load(reinterpret_cast<const u64*>(p), __ATOMIC_RELAXED,
                           __HIP_MEMORY_SCOPE_AGENT);
}

// bf16 pack (round-to-nearest-even) / unpack
__device__ __forceinline__ unsigned rtne16(float x) {
  const unsigned u = __float_as_uint(x);
  return u + 0x7fffu + ((u >> 16) & 1u);
}
__device__ __forceinline__ unsigned pk(float lo, float hi) {
  return (rtne16(lo) >> 16) | (rtne16(hi) & 0xffff0000u);
}
__device__ __forceinline__ float bflo(unsigned p) {
  return __uint_as_float(p << 16);
}
__device__ __forceinline__ float bfhi(unsigned p) {
  return __uint_as_float(p & 0xffff0000u);
}

__global__ void zero_kernel(float* __restrict__ ws) {
  const int i = blockIdx.x * blockDim.x + threadIdx.x;
  if (i < WS_FLOATS) ws[i] = 0.f;
}

// Fused: phase1 streams HBM once (ALL loads straight-lined) + bf16 LDS
// cache -> per-batch spin barrier -> phase3 re-reads from LDS only.
__global__ __launch_bounds__(NT, 8) void fused_kernel(
    const float* __restrict__ emb, const int* __restrict__ lab,
    float* __restrict__ ws, float* __restrict__ out) {
  const int b = blockIdx.x >> 8, bxl = blockIdx.x & (GPB - 1);
  const int tid = threadIdx.x, wv = tid >> 6, ln = tid & 63;

  __shared__ unsigned e01[GRP_BLK * 4];  // 8 KB: pixel -> bf16(c0,c1)
  __shared__ unsigned e23[GRP_BLK * 4];  // 8 KB: pixel -> bf16(c2,c3)
  __shared__ unsigned labp[GRP_BLK];     // 2 KB: 4 labels/u32
  __shared__ float red[4][25];
  __shared__ float stot[25];
  __shared__ float sm[K][C];
  __shared__ float scnt[K];
  __shared__ float rcnt[8];  // rcnt[l] = (l==0) ? 0 : 1/cnt[l-1]
  __shared__ float red2[4];
  __shared__ unsigned lastFlag;

  const float4* __restrict__ ep =
      reinterpret_cast<const float4*>(emb + (size_t)b * C * HW);
  const int4* __restrict__ lp =
      reinterpret_cast<const int4*>(lab + (size_t)b * HW);

  // -------- Phase 1: single HBM sweep, ALL 10 loads issued up front -------
  const int lgA = tid, lgB = NT + tid;          // local groups
  const int gA = bxl * GRP_BLK + lgA, gB = bxl * GRP_BLK + lgB;
  const int4 laA = lp[gA], laB = lp[gB];
  const float4 A0 = ep[gA], A1 = ep[NG + gA], A2 = ep[2 * NG + gA],
               A3 = ep[3 * NG + gA];
  const float4 B0 = ep[gB], B1 = ep[NG + gB], B2 = ep[2 * NG + gB],
               B3 = ep[3 * NG + gB];

  float acc[25];  // [k][{c0..c3,cnt}] flat, compile-time indexed only
#pragma unroll
  for (int i = 0; i < 25; i++) acc[i] = 0.f;
  auto accum1 = [&](int l, float v0, float v1, float v2, float v3) {
#pragma unroll
    for (int k = 0; k < K; k++) {  // branchless predicated accumulate
      const float m = (l == k + 1) ? 1.f : 0.f;
      acc[k * 5 + 0] = fmaf(m, v0, acc[k * 5 + 0]);
      acc[k * 5 + 1] = fmaf(m, v1, acc[k * 5 + 1]);
      acc[k * 5 + 2] = fmaf(m, v2, acc[k * 5 + 2]);
      acc[k * 5 + 3] = fmaf(m, v3, acc[k * 5 + 3]);
      acc[k * 5 + 4] += m;
    }
  };
  accum1(laA.x, A0.x, A1.x, A2.x, A3.x);
  accum1(laA.y, A0.y, A1.y, A2.y, A3.y);
  accum1(laA.z, A0.z, A1.z, A2.z, A3.z);
  accum1(laA.w, A0.w, A1.w, A2.w, A3.w);
  accum1(laB.x, B0.x, B1.x, B2.x, B3.x);
  accum1(laB.y, B0.y, B1.y, B2.y, B3.y);
  accum1(laB.z, B0.z, B1.z, B2.z, B3.z);
  accum1(laB.w, B0.w, B1.w, B2.w, B3.w);

  {  // cache pixels to LDS as bf16 pairs + packed labels
    uint4 w01, w23;
    w01.x = pk(A0.x, A1.x); w23.x = pk(A2.x, A3.x);
    w01.y = pk(A0.y, A1.y); w23.y = pk(A2.y, A3.y);
    w01.z = pk(A0.z, A1.z); w23.z = pk(A2.z, A3.z);
    w01.w = pk(A0.w, A1.w); w23.w = pk(A2.w, A3.w);
    *reinterpret_cast<uint4*>(&e01[lgA * 4]) = w01;
    *reinterpret_cast<uint4*>(&e23[lgA * 4]) = w23;
    labp[lgA] = (unsigned)(laA.x & 0xff) | ((unsigned)(laA.y & 0xff) << 8) |
                ((unsigned)(laA.z & 0xff) << 16) |
                ((unsigned)(laA.w & 0xff) << 24);
    w01.x = pk(B0.x, B1.x); w23.x = pk(B2.x, B3.x);
    w01.y = pk(B0.y, B1.y); w23.y = pk(B2.y, B3.y);
    w01.z = pk(B0.z, B1.z); w23.z = pk(B2.z, B3.z);
    w01.w = pk(B0.w, B1.w); w23.w = pk(B2.w, B3.w);
    *reinterpret_cast<uint4*>(&e01[lgB * 4]) = w01;
    *reinterpret_cast<uint4*>(&e23[lgB * 4]) = w23;
    labp[lgB] = (unsigned)(laB.x & 0xff) | ((unsigned)(laB.y & 0xff) << 8) |
                ((unsigned)(laB.z & 0xff) << 16) |
                ((unsigned)(laB.w & 0xff) << 24);
  }

#pragma unroll
  for (int i = 0; i < 25; i++) {
    const float v = wave_reduce(acc[i]);
    if (ln == 0) red[wv][i] = v;
  }
  __syncthreads();
  if (tid < 25) {  // publish stats: integer atomicAdd, 64-long chains
    const float t =
        (red[0][tid] + red[1][tid]) + (red[2][tid] + red[3][tid]);
    const long long q = (long long)((double)t * FXST);
    atomicAdd(reinterpret_cast<u64*>(
                  ws + ST_OFF +
                  ((size_t)(b * 25 + tid) * SS + (bxl & (SS - 1))) * LINE),
              (u64)q);
  }

  // per-batch barrier: two-level arrival + backoff spin
  if (tid == 0) {
    asm volatile("s_waitcnt vmcnt(0)" ::: "memory");  // drain publishes
    unsigned* c1s = reinterpret_cast<unsigned*>(
        ws + C1S_OFF + ((size_t)b * SS + (bxl & (SS - 1))) * LINE);
    const unsigned olds = atomicAdd(c1s, 1u);
    if (olds == (unsigned)(GPB / SS - 1)) {  // sub-group finisher
      asm volatile("s_waitcnt vmcnt(0)" ::: "memory");
      atomicAdd(reinterpret_cast<unsigned*>(ws + C1M_OFF + (size_t)b * LINE),
                1u);
    }
    const unsigned* c1m =
        reinterpret_cast<const unsigned*>(ws + C1M_OFF + (size_t)b * LINE);
    while (__hip_atomic_load(c1m, __ATOMIC_RELAXED,
                             __HIP_MEMORY_SCOPE_AGENT) < (unsigned)SS) {
      __builtin_amdgcn_s_sleep(32);  // ~2k cycles: pollers stay off the bus
    }
  }
  __syncthreads();
  asm volatile("" ::: "memory");

  // ---------------- Phase 2: read batch stats -> means ----------------
  if (tid < 25) {
    long long s = 0;
#pragma unroll
    for (int j = 0; j < SS; j++)
      s += (long long)aload64(ws + ST_OFF +
                              ((size_t)(b * 25 + tid) * SS + j) * LINE);
    stot[tid] = (float)((double)s / FXST);
  }
  __syncthreads();
  if (tid < K * C) {
    const int k = tid / C, c = tid % C;
    sm[k][c] = stot[k * 5 + c] / stot[k * 5 + 4];
  }
  if (tid < K) scnt[tid] = stot[tid * 5 + 4];
  if (tid < 8) rcnt[tid] = 0.f;
  __syncthreads();
  if (tid < K) rcnt[tid + 1] = 1.f / scnt[tid];
  __syncthreads();

  // ------- Phase 3: LDS-only sweep, straight-lined reads ----------------
  const uint4 rA01 = *reinterpret_cast<const uint4*>(&e01[lgA * 4]);
  const uint4 rA23 = *reinterpret_cast<const uint4*>(&e23[lgA * 4]);
  const unsigned lwA = labp[lgA];
  const uint4 rB01 = *reinterpret_cast<const uint4*>(&e01[lgB * 4]);
  const uint4 rB23 = *reinterpret_cast<const uint4*>(&e23[lgB * 4]);
  const unsigned lwB = labp[lgB];

  float vacc = 0.f;  // sum of t^2/cnt[lane] (exactly one lane per pixel)
  auto accum2 = [&](int l, float v0, float v1, float v2, float v3) {
    const int kk = (l > 0) ? (l - 1) : 0;  // safe index; l==0 -> rcnt[0]==0
    const float d0 = v0 - sm[kk][0];
    const float d1 = v1 - sm[kk][1];
    const float d2 = v2 - sm[kk][2];
    const float d3 = v3 - sm[kk][3];
    const float t =
        fmaxf(sqrtf(d0 * d0 + d1 * d1 + d2 * d2 + d3 * d3) - DV, 0.f);
    vacc = fmaf(t * t, rcnt[l], vacc);
  };
  accum2((int)(lwA & 0xffu), bflo(rA01.x), bfhi(rA01.x), bflo(rA23.x),
         bfhi(rA23.x));
  accum2((int)((lwA >> 8) & 0xffu), bflo(rA01.y), bfhi(rA01.y), bflo(rA23.y),
         bfhi(rA23.y));
  accum2((int)((lwA >> 16) & 0xffu), bflo(rA01.z), bfhi(rA01.z), bflo(rA23.z),
         bfhi(rA23.z));
  accum2((int)((lwA >> 24) & 0xffu), bflo(rA01.w), bfhi(rA01.w), bflo(rA23.w),
         bfhi(rA23.w));
  accum2((int)(lwB & 0xffu), bflo(rB01.x), bfhi(rB01.x), bflo(rB23.x),
         bfhi(rB23.x));
  accum2((int)((lwB >> 8) & 0xffu), bflo(rB01.y), bfhi(rB01.y), bflo(rB23.y),
         bfhi(rB23.y));
  accum2((int)((lwB >> 16) & 0xffu), bflo(rB01.z), bfhi(rB01.z), bflo(rB23.z),
         bfhi(rB23.z));
  accum2((int)((lwB >> 24) & 0xffu), bflo(rB01.w), bfhi(rB01.w), bflo(rB23.w),
         bfhi(rB23.w));

  {
    const float v = wave_reduce(vacc);
    if (ln == 0) red2[wv] = v;
  }
  __syncthreads();

  if (tid == 0) {
    const float sblk = (red2[0] + red2[1]) + (red2[2] + red2[3]);
    const u64 fx = (u64)(long long)((double)sblk * FXSV);
    atomicAdd(reinterpret_cast<u64*>(
                  ws + IACC_OFF + ((size_t)b * SS + (bxl & (SS - 1))) * LINE),
              fx);
    asm volatile("s_waitcnt vmcnt(0)" ::: "memory");
    unsigned* c2s = reinterpret_cast<unsigned*>(
        ws + C2S_OFF + ((size_t)b * SS + (bxl & (SS - 1))) * LINE);
    const unsigned olds = atomicAdd(c2s, 1u);
    unsigned lf = 0u;
    if (olds == (unsigned)(GPB / SS - 1)) {
      asm volatile("s_waitcnt vmcnt(0)" ::: "memory");
      unsigned* gc = reinterpret_cast<unsigned*>(ws + GC_OFF);
      const unsigned oldg = atomicAdd(gc, 1u);
      lf = (oldg == (unsigned)(B * SS - 1)) ? 1u : 0u;
    }
    lastFlag = lf;
  }
  __syncthreads();
  if (!lastFlag) return;

  // ---------------- Finalize (unique global-last block) ----------------
  __shared__ float stF[B * 25];
  __shared__ float sb[B];
  if (tid < B * 25) {
    long long s = 0;
#pragma unroll
    for (int j = 0; j < SS; j++)
      s += (long long)aload64(ws + ST_OFF + ((size_t)tid * SS + j) * LINE);
    stF[tid] = (float)((double)s / FXST);
  }
  if (tid < B) {
    long long s = 0;
#pragma unroll
    for (int j = 0; j < SS; j++)
      s += (long long)aload64(ws + IACC_OFF + ((size_t)tid * SS + j) * LINE);
    sb[tid] = (float)((double)s / FXSV);
  }
  __syncthreads();
  if (tid != 0) return;

  float v = 0.f, d = 0.f;
  for (int bb = 0; bb < B; bb++) {
    float m[K][C];
#pragma unroll
    for (int k = 0; k < K; k++) {
      const float cnt = stF[bb * 25 + k * 5 + 4];
#pragma unroll
      for (int c = 0; c < C; c++) m[k][c] = stF[bb * 25 + k * 5 + c] / cnt;
    }
    float p = 0.f;
#pragma unroll
    for (int i = 0; i < K; i++) {
#pragma unroll
      for (int j = 0; j < K; j++) {
        if (i == j) continue;  // diagonal term is exactly 0
        float dd = 0.f;
#pragma unroll
        for (int c = 0; c < C; c++) {
          const float t = m[i][c] - m[j][c];
          dd += t * t;
        }
        const float r = fmaxf(DD - sqrtf(dd), 0.f);
        p += r * r;
      }
    }
    v = (v + sb[bb]) / (float)K;
    d = (d + p) / (float)(2 * K * (K - 1));
  }
  out[0] = v / (float)B;
  out[1] = d / (float)B;
}

}  // namespace

extern "C" void kernel_launch(void* const* d_in, const int* in_sizes, int n_in,
                              void* d_out, int out_size, void* d_ws,
                              size_t ws_size, hipStream_t stream) {
  const float* emb = (const float*)d_in[0];
  const int* lab = (const int*)d_in[1];
  float* out = (float*)d_out;
  float* ws = (float*)d_ws;

  zero_kernel<<<(WS_FLOATS + NT - 1) / NT, NT, 0, stream>>>(ws);
  fused_kernel<<<NBLK, NT, 0, stream>>>(emb, lab, ws, out);
}